// Round 2
// baseline (1258.133 us; speedup 1.0000x reference)
//
#include <hip/hip_runtime.h>

#define NB 2048
#define NT 1024

// sigmoid via native exp2 + rcp (v_exp_f32, v_rcp_f32)
__device__ __forceinline__ float sig_fast(float x) {
    return __builtin_amdgcn_rcpf(1.0f + exp2f(-1.4426950408889634f * x));
}
// tanh(x) = 2*sigmoid(2x) - 1
__device__ __forceinline__ float tanh_fast(float x) {
    return fmaf(2.0f, __builtin_amdgcn_rcpf(1.0f + exp2f(-2.8853900817779268f * x)), -1.0f);
}

__global__ void zero_loss_kernel(float* out) { out[0] = 0.0f; }

#define LD4(P, i) (*(const float4*)&(P)[i])

// 8 named float4 = one 32-wide weight row, guaranteed register-resident (SSA values)
#define DECL_ROW(n, src, row)                  \
  const float4 n##0 = LD4(src, (row)*32 +  0); \
  const float4 n##1 = LD4(src, (row)*32 +  4); \
  const float4 n##2 = LD4(src, (row)*32 +  8); \
  const float4 n##3 = LD4(src, (row)*32 + 12); \
  const float4 n##4 = LD4(src, (row)*32 + 16); \
  const float4 n##5 = LD4(src, (row)*32 + 20); \
  const float4 n##6 = LD4(src, (row)*32 + 24); \
  const float4 n##7 = LD4(src, (row)*32 + 28);

#define MAC4(aa, ab, wA, wB, h)                                \
  aa = fmaf((wA).x, (h).x, aa); ab = fmaf((wB).x, (h).x, ab);  \
  aa = fmaf((wA).y, (h).y, aa); ab = fmaf((wB).y, (h).y, ab);  \
  aa = fmaf((wA).z, (h).z, aa); ab = fmaf((wB).z, (h).z, ab);  \
  aa = fmaf((wA).w, (h).w, aa); ab = fmaf((wB).w, (h).w, ab);

__global__ __launch_bounds__(64, 2)
void decoder_lstm_kernel(const float* __restrict__ seq,    // (B,T,1)
                         const float* __restrict__ z,      // (B,32)
                         const float* __restrict__ w_ih0,  // (128,1)
                         const float* __restrict__ w_hh0,  // (128,32)
                         const float* __restrict__ b_ih0,  // (128,)
                         const float* __restrict__ b_hh0,  // (128,)
                         const float* __restrict__ w_ih1,  // (128,32)
                         const float* __restrict__ w_hh1,  // (128,32)
                         const float* __restrict__ b_ih1,  // (128,)
                         const float* __restrict__ b_hh1,  // (128,)
                         const float* __restrict__ w_out,  // (1,32)
                         const float* __restrict__ b_out,  // (1,)
                         float* __restrict__ out)          // [0]=loss, [1..]=recovered (B,T,1)
{
    const int b  = blockIdx.x;     // one wave per batch element
    const int l  = threadIdx.x;    // 0..63
    const int lo = l & 31;

    // 64-float rows: slots 32..63 are padding so ALL lanes can store unconditionally
    __shared__ float4 sh0[16];
    __shared__ float4 sh1[16];

    // lane<32 : rA=i-row, rB=g-row ; lane>=32: rA=f-row, rB=o-row
    const int rA = l;
    const int rB = l + 64;

    const float wih0A  = w_ih0[rA];
    const float wih0B  = w_ih0[rB];
    const float bias0A = b_ih0[rA] + b_hh0[rA];
    const float bias0B = b_ih0[rB] + b_hh0[rB];
    const float bias1A = b_ih1[rA] + b_hh1[rA];
    const float bias1B = b_ih1[rB] + b_hh1[rB];

    // 48 named float4 = 192 VGPRs of weights. Registers are the only storage
    // tier with enough BW (LDS pipe is per-CU and would be ~3x oversubscribed).
    DECL_ROW(w0A, w_hh0, rA)
    DECL_ROW(w0B, w_hh0, rB)
    DECL_ROW(wiA, w_ih1, rA)
    DECL_ROW(wiB, w_ih1, rB)
    DECL_ROW(whA, w_hh1, rA)
    DECL_ROW(whB, w_hh1, rB)

    const float wOut = (l < 32) ? w_out[lo] : 0.0f;  // 0 on upper lanes -> clean reduction
    const float bOut = b_out[0];

    // init: h0 = c0 = h1 = c1 = z, pred = 0
    float zv = z[(size_t)b * 32 + lo];
    ((float*)sh0)[l] = zv;        // upper lanes land in padding
    ((float*)sh1)[l] = zv;
    float cc0 = zv, cc1 = zv;
    float pred = 0.0f, sse = 0.0f, xreg = 0.0f;

    const float* seq_b = seq + (size_t)b * NT;
    float* out_b = out + 1 + (size_t)b * NT;

    __builtin_amdgcn_wave_barrier();   // single wave: DS ops execute in order; fence compiler only

    for (int t = 0; t < NT; ++t) {
        // one coalesced 256B load per 64 steps; lane (t&63) owns step t's residual
        if ((t & 63) == 0) xreg = seq_b[t + l];

        // ---------------- cell 0: gates = pred*w_ih0 + h0 @ w_hh0^T + b0
        float a0 = fmaf(pred, wih0A, bias0A);
        float b0 = fmaf(pred, wih0B, bias0B);
        float a1 = 0.0f, b1 = 0.0f;
        float4 h;
        h = sh0[0]; MAC4(a0, b0, w0A0, w0B0, h);
        h = sh0[1]; MAC4(a1, b1, w0A1, w0B1, h);
        h = sh0[2]; MAC4(a0, b0, w0A2, w0B2, h);
        h = sh0[3]; MAC4(a1, b1, w0A3, w0B3, h);
        h = sh0[4]; MAC4(a0, b0, w0A4, w0B4, h);
        h = sh0[5]; MAC4(a1, b1, w0A5, w0B5, h);
        h = sh0[6]; MAC4(a0, b0, w0A6, w0B6, h);
        h = sh0[7]; MAC4(a1, b1, w0A7, w0B7, h);
        float gA = a0 + a1;   // lane<32: i ; lane>=32: f
        float gB = b0 + b1;   // lane<32: g ; lane>=32: o

        float sA   = sig_fast(gA);
        float argB = (l < 32) ? (gB + gB) : gB;          // tanh via 2*sig(2x)-1
        float sB   = sig_fast(argB);
        float vB   = (l < 32) ? fmaf(2.0f, sB, -1.0f) : sB;  // tanh(g) / sig(o)

        float fOrI = __shfl_xor(sA, 32);   // lane<32 receives sig(f)
        float oOrG = __shfl_xor(vB, 32);   // lane<32 receives sig(o)
        cc0 = fmaf(fOrI, cc0, sA * vB);          // lanes<32 valid
        float h0n = oOrG * tanh_fast(cc0);
        ((float*)sh0)[l] = h0n;                  // upper-lane garbage -> padding (finite)
        __builtin_amdgcn_wave_barrier();

        // ---------------- cell 1: gates = h0n @ w_ih1^T + h1 @ w_hh1^T + b1
        float cA0 = bias1A, cB0 = bias1B;
        float cA1 = 0.0f,  cB1 = 0.0f;
        float4 u;
        u = sh0[0]; MAC4(cA0, cB0, wiA0, wiB0, u);
        u = sh1[0]; MAC4(cA1, cB1, whA0, whB0, u);
        u = sh0[1]; MAC4(cA0, cB0, wiA1, wiB1, u);
        u = sh1[1]; MAC4(cA1, cB1, whA1, whB1, u);
        u = sh0[2]; MAC4(cA0, cB0, wiA2, wiB2, u);
        u = sh1[2]; MAC4(cA1, cB1, whA2, whB2, u);
        u = sh0[3]; MAC4(cA0, cB0, wiA3, wiB3, u);
        u = sh1[3]; MAC4(cA1, cB1, whA3, whB3, u);
        u = sh0[4]; MAC4(cA0, cB0, wiA4, wiB4, u);
        u = sh1[4]; MAC4(cA1, cB1, whA4, whB4, u);
        u = sh0[5]; MAC4(cA0, cB0, wiA5, wiB5, u);
        u = sh1[5]; MAC4(cA1, cB1, whA5, whB5, u);
        u = sh0[6]; MAC4(cA0, cB0, wiA6, wiB6, u);
        u = sh1[6]; MAC4(cA1, cB1, whA6, whB6, u);
        u = sh0[7]; MAC4(cA0, cB0, wiA7, wiB7, u);
        u = sh1[7]; MAC4(cA1, cB1, whA7, whB7, u);
        float g1A = cA0 + cA1;
        float g1B = cB0 + cB1;

        float s1A   = sig_fast(g1A);
        float arg1B = (l < 32) ? (g1B + g1B) : g1B;
        float s1B   = sig_fast(arg1B);
        float v1B   = (l < 32) ? fmaf(2.0f, s1B, -1.0f) : s1B;

        float f1 = __shfl_xor(s1A, 32);
        float o1 = __shfl_xor(v1B, 32);
        cc1 = fmaf(f1, cc1, s1A * v1B);
        float h1n = o1 * tanh_fast(cc1);          // lanes<32 valid, upper finite garbage
        ((float*)sh1)[l] = h1n;

        // pred = b_out + sum_j w_out[j]*h1n[j]  (upper lanes contribute 0 via wOut=0)
        float term = wOut * h1n;
        term += __shfl_xor(term, 1);
        term += __shfl_xor(term, 2);
        term += __shfl_xor(term, 4);
        term += __shfl_xor(term, 8);
        term += __shfl_xor(term, 16);
        term += __shfl_xor(term, 32);
        pred = term + bOut;
        __builtin_amdgcn_wave_barrier();

        out_b[t] = pred;                         // same value/address across lanes
        float d = xreg - pred;
        sse = fmaf(((t & 63) == l) ? d : 0.0f, d, sse);
    }

    // wave-wide SSE reduction, one atomic per block
    sse += __shfl_xor(sse, 1);
    sse += __shfl_xor(sse, 2);
    sse += __shfl_xor(sse, 4);
    sse += __shfl_xor(sse, 8);
    sse += __shfl_xor(sse, 16);
    sse += __shfl_xor(sse, 32);
    if (l == 0) {
        atomicAdd(out, sse * (1.0f / ((float)NB * (float)NT)));  // 1/(B*T) = 2^-21 exact
    }
}

extern "C" void kernel_launch(void* const* d_in, const int* in_sizes, int n_in,
                              void* d_out, int out_size, void* d_ws, size_t ws_size,
                              hipStream_t stream) {
    const float* seq   = (const float*)d_in[0];
    const float* z     = (const float*)d_in[1];
    // d_in[2] = lengths (unused; reference ignores it)
    const float* w_ih0 = (const float*)d_in[3];
    const float* w_hh0 = (const float*)d_in[4];
    const float* b_ih0 = (const float*)d_in[5];
    const float* b_hh0 = (const float*)d_in[6];
    const float* w_ih1 = (const float*)d_in[7];
    const float* w_hh1 = (const float*)d_in[8];
    const float* b_ih1 = (const float*)d_in[9];
    const float* b_hh1 = (const float*)d_in[10];
    const float* w_out = (const float*)d_in[11];
    const float* b_out = (const float*)d_in[12];
    float* out = (float*)d_out;

    hipLaunchKernelGGL(zero_loss_kernel, dim3(1), dim3(1), 0, stream, out);
    hipLaunchKernelGGL(decoder_lstm_kernel, dim3(NB), dim3(64), 0, stream,
                       seq, z, w_ih0, w_hh0, b_ih0, b_hh0,
                       w_ih1, w_hh1, b_ih1, b_hh1, w_out, b_out, out);
}